// Round 1
// baseline (1572.352 us; speedup 1.0000x reference)
//
#include <hip/hip_runtime.h>
#include <hip/hip_bf16.h>

// ---------------------------------------------------------------------------
// SelfAttentionModule: concat(f_rgb,f_i) -> 1x1 conv Q,K,V -> softmax(QK^T/64)
// -> V @ attn^T -> fold halves.
// Outputs (flat, in order): f_final [2,2048,64,64], f_rgb copy, f_i copy,
//                           attn [2,4096,4096].
// Plan (all GEMMs in "A row-major K-contig, B^T row-major K-contig" m97 form):
//   pack_xt   : Xt[b][n][c2] bf16 (transpose+concat) + fp32 passthrough copies
//   G1        : QKt[b][n][o] = Xt . [wq;wk]^T + bqk   (4096x4096x4096, bf16)
//   GV        : Vsum[b][c][m] = (wv[c]+wv[c+2048]) . Xt^T + bvsum (2048x4096x4096)
//   G2        : S[b][n][m] = Qt.Kt^T / 64  -> d_out attn region (fp32)
//   softmax   : in-place rows of S -> attn fp32 + attn bf16 (ws)
//   G3        : f_final[b][c][n] = Vsum . attn_bf^T (2048x4096x4096, fp32)
// ws budget ~285 MB.
// ---------------------------------------------------------------------------

#define B_   2
#define C_   2048
#define N_   4096
#define C2_  4096

typedef __hip_bfloat16 bf16_t;
typedef __bf16 bf16x8 __attribute__((ext_vector_type(8)));
typedef float floatx4 __attribute__((ext_vector_type(4)));

__device__ inline void load_lds16(const void* g, void* l) {
  __builtin_amdgcn_global_load_lds(
      (const __attribute__((address_space(1))) void*)g,
      (__attribute__((address_space(3))) void*)l, 16, 0, 0);
}

__device__ inline unsigned short f2bf(float f) {
  return __builtin_bit_cast(unsigned short, __float2bfloat16(f));
}

__device__ inline void cstore(float* p, float v)  { *p = v; }
__device__ inline void cstore(bf16_t* p, float v) { *p = __float2bfloat16(v); }

// ---------------------------------------------------------------------------
// GEMM: C[i][j] = scale * sum_k A[i][k]*Bt[j][k] + bias_m[i] + bias_n[j]
// 128x128 tile, BK=32, 256 threads (4 waves, 2x2 of 64x64), bf16 MFMA 16x16x32.
// M,N multiples of 128; K multiple of 32. grid = (N/128, M/128, batch).
// ---------------------------------------------------------------------------
template <typename OutT>
__global__ __launch_bounds__(256) void gemm_bt(
    const bf16_t* __restrict__ A, const bf16_t* __restrict__ Bt,
    OutT* __restrict__ Cm, int K, int lda, int ldb, int ldc,
    long long abst, long long bbst, long long cbst,
    const float* __restrict__ bias_m, const float* __restrict__ bias_n,
    float scale)
{
  __shared__ __align__(16) bf16_t lds_a[128 * 32];
  __shared__ __align__(16) bf16_t lds_b[128 * 32];

  const int tid  = threadIdx.x;
  const int lane = tid & 63;
  const int wave = tid >> 6;
  const long long bM = (long long)blockIdx.y * 128;
  const long long bN = (long long)blockIdx.x * 128;

  const bf16_t* Ab = A  + (long long)blockIdx.z * abst;
  const bf16_t* Bb = Bt + (long long)blockIdx.z * bbst;
  OutT*         Cb = Cm + (long long)blockIdx.z * cbst;

  // staging: per wave-issue, 64 lanes fill 1024 contiguous LDS bytes = 16 rows
  // of 32 bf16. lane i -> row i/4, byte (i%4)*16. LDS dest = base + lane*16.
  const int srow = lane >> 2;          // 0..15
  const int scol = (lane & 3) * 8;     // k elements
  const bf16_t* ga = Ab + (bM + wave * 32 + srow) * (long long)lda + scol;
  const bf16_t* gb = Bb + (bN + wave * 32 + srow) * (long long)ldb + scol;
  bf16_t* la = &lds_a[(wave * 32) * 32];
  bf16_t* lb = &lds_b[(wave * 32) * 32];

  const int wm = (wave >> 1) * 64;
  const int wn = (wave & 1) * 64;
  const int fr = lane & 15;            // fragment row (A m / B n)
  const int kq = (lane >> 4) * 8;      // fragment k-chunk

  floatx4 acc[4][4];
#pragma unroll
  for (int i = 0; i < 4; i++)
#pragma unroll
    for (int j = 0; j < 4; j++) acc[i][j] = (floatx4){0.f, 0.f, 0.f, 0.f};

  for (int k0 = 0; k0 < K; k0 += 32) {
    load_lds16(ga,            la);
    load_lds16(ga + 16 * (long long)lda, la + 16 * 32);
    load_lds16(gb,            lb);
    load_lds16(gb + 16 * (long long)ldb, lb + 16 * 32);
    ga += 32; gb += 32;
    __syncthreads();

    bf16x8 af[4], bfr[4];
#pragma unroll
    for (int mi = 0; mi < 4; mi++)
      af[mi] = *(const bf16x8*)&lds_a[(wm + mi * 16 + fr) * 32 + kq];
#pragma unroll
    for (int ni = 0; ni < 4; ni++)
      bfr[ni] = *(const bf16x8*)&lds_b[(wn + ni * 16 + fr) * 32 + kq];
#pragma unroll
    for (int mi = 0; mi < 4; mi++)
#pragma unroll
      for (int ni = 0; ni < 4; ni++)
        acc[mi][ni] = __builtin_amdgcn_mfma_f32_16x16x32_bf16(
            af[mi], bfr[ni], acc[mi][ni], 0, 0, 0);
    __syncthreads();
  }

  // epilogue: C/D layout col=lane&15, row=(lane>>4)*4+r  [m89-verified]
  const int rown = (lane >> 4) * 4;
#pragma unroll
  for (int mi = 0; mi < 4; mi++) {
#pragma unroll
    for (int ni = 0; ni < 4; ni++) {
      const long long n = bN + wn + ni * 16 + fr;
      const float bnv = bias_n ? bias_n[n] : 0.f;
#pragma unroll
      for (int r = 0; r < 4; r++) {
        const long long m = bM + wm + mi * 16 + rown + r;
        const float bmv = bias_m ? bias_m[m] : 0.f;
        cstore(&Cb[m * (long long)ldc + n], acc[mi][ni][r] * scale + bnv + bmv);
      }
    }
  }
}

// ---------------------------------------------------------------------------
// pack_xt: per 64(c)x64(n) tile of one source (z = b*2 + which):
//   read fp32 coalesced, write passthrough copy, LDS-transpose, write Xt bf16.
// ---------------------------------------------------------------------------
__global__ __launch_bounds__(256) void pack_xt(
    const float* __restrict__ f_rgb, const float* __restrict__ f_i,
    float* __restrict__ out_rgb, float* __restrict__ out_i,
    bf16_t* __restrict__ xt)
{
  const int b  = blockIdx.z >> 1;
  const int wh = blockIdx.z & 1;
  const float* src = (wh ? f_i : f_rgb) + (long long)b * C_ * N_;
  float*       pt  = (wh ? out_i : out_rgb) + (long long)b * C_ * N_;
  const int c0 = blockIdx.y * 64, n0 = blockIdx.x * 64;
  __shared__ float tile[64][65];

  const int tid = threadIdx.x;
  {
    const int tn = tid & 63, tc4 = tid >> 6;
#pragma unroll
    for (int r = 0; r < 16; r++) {
      const int c = tc4 * 16 + r;
      const long long idx = (long long)(c0 + c) * N_ + n0 + tn;
      const float v = src[idx];
      pt[idx] = v;
      tile[tn][c] = v;
    }
  }
  __syncthreads();
  {
    const int tc = tid & 63, tn4 = tid >> 6;
#pragma unroll
    for (int r = 0; r < 16; r++) {
      const int n = tn4 * 16 + r;
      xt[((long long)b * N_ + n0 + n) * C2_ + wh * C_ + c0 + tc] =
          __float2bfloat16(tile[n][tc]);
    }
  }
}

// wqk_bf[o][c]: rows 0..2047 = wq, 2048..4095 = wk (bf16)
__global__ __launch_bounds__(256) void conv_wqk(
    const float* __restrict__ wq, const float* __restrict__ wk,
    unsigned short* __restrict__ dst)
{
  const long long i = ((long long)blockIdx.x * 256 + threadIdx.x) * 4;
  const int o = (int)(i >> 12);
  const long long c = i & 4095;
  const float* src = (o < C_) ? (wq + (long long)o * C2_ + c)
                              : (wk + (long long)(o - C_) * C2_ + c);
  const float4 f = *(const float4*)src;
  *(ushort4*)(dst + i) = make_ushort4(f2bf(f.x), f2bf(f.y), f2bf(f.z), f2bf(f.w));
}

// wvsum_bf[c][c2] = bf16(wv[c][c2] + wv[c+2048][c2])
__global__ __launch_bounds__(256) void conv_wvsum(
    const float* __restrict__ wv, unsigned short* __restrict__ dst)
{
  const long long i = ((long long)blockIdx.x * 256 + threadIdx.x) * 4;
  const float4 a = *(const float4*)(wv + i);
  const float4 b = *(const float4*)(wv + i + (long long)C_ * C2_);
  *(ushort4*)(dst + i) = make_ushort4(f2bf(a.x + b.x), f2bf(a.y + b.y),
                                      f2bf(a.z + b.z), f2bf(a.w + b.w));
}

__global__ __launch_bounds__(256) void conv_bias(
    const float* __restrict__ bq, const float* __restrict__ bk,
    const float* __restrict__ bv, float* __restrict__ bqk,
    float* __restrict__ bvsum)
{
  const int i = blockIdx.x * 256 + threadIdx.x;   // < 4096
  bqk[i] = (i < C_) ? bq[i] : bk[i - C_];
  if (i < C_) bvsum[i] = bv[i] + bv[i + C_];
}

// in-place row softmax on d_out attn region + bf16 copy. 1 block per row.
__global__ __launch_bounds__(256) void softmax_rows(
    float* __restrict__ attn, bf16_t* __restrict__ attn_bf)
{
  const long long row = blockIdx.x;   // 0 .. B*N-1
  float*  p  = attn    + row * N_;
  bf16_t* pb = attn_bf + row * N_;
  const int tid = threadIdx.x;
  const int lane = tid & 63, wave = tid >> 6;

  float v[16];
  float mx = -3.4e38f;
#pragma unroll
  for (int i = 0; i < 16; i++) { v[i] = p[tid + i * 256]; mx = fmaxf(mx, v[i]); }
#pragma unroll
  for (int off = 32; off >= 1; off >>= 1) mx = fmaxf(mx, __shfl_xor(mx, off, 64));

  __shared__ float redm[4];
  __shared__ float reds[4];
  if (lane == 0) redm[wave] = mx;
  __syncthreads();
  mx = fmaxf(fmaxf(redm[0], redm[1]), fmaxf(redm[2], redm[3]));

  float s = 0.f;
#pragma unroll
  for (int i = 0; i < 16; i++) { v[i] = __expf(v[i] - mx); s += v[i]; }
#pragma unroll
  for (int off = 32; off >= 1; off >>= 1) s += __shfl_xor(s, off, 64);
  if (lane == 0) reds[wave] = s;
  __syncthreads();
  s = reds[0] + reds[1] + reds[2] + reds[3];
  const float inv = 1.f / s;
#pragma unroll
  for (int i = 0; i < 16; i++) {
    const float a = v[i] * inv;
    p[tid + i * 256]  = a;
    pb[tid + i * 256] = __float2bfloat16(a);
  }
}

extern "C" void kernel_launch(void* const* d_in, const int* in_sizes, int n_in,
                              void* d_out, int out_size, void* d_ws, size_t ws_size,
                              hipStream_t stream) {
  const float* f_rgb = (const float*)d_in[0];
  const float* f_i   = (const float*)d_in[1];
  const float* wq    = (const float*)d_in[2];
  const float* bq    = (const float*)d_in[3];
  const float* wk    = (const float*)d_in[4];
  const float* bk    = (const float*)d_in[5];
  const float* wv    = (const float*)d_in[6];
  const float* bv    = (const float*)d_in[7];

  float* out       = (float*)d_out;
  float* out_ff    = out;                                  // [2][2048][4096]
  float* out_rgb   = out + (size_t)B_ * C_ * N_;
  float* out_fi    = out_rgb + (size_t)B_ * C_ * N_;
  float* out_attn  = out_fi + (size_t)B_ * C_ * N_;        // [2][4096][4096]

  // workspace layout (256-B aligned)
  char* ws = (char*)d_ws;
  size_t off = 0;
  auto alloc = [&](size_t bytes) {
    size_t o = off; off += (bytes + 255) & ~(size_t)255; return o;
  };
  bf16_t* xt   = (bf16_t*)(ws + alloc((size_t)B_ * N_ * C2_ * 2));   // 64 MiB
  bf16_t* wqk  = (bf16_t*)(ws + alloc((size_t)C2_ * C2_ * 2));       // 32 MiB
  bf16_t* wvs  = (bf16_t*)(ws + alloc((size_t)C_ * C2_ * 2));        // 16 MiB
  bf16_t* qkt  = (bf16_t*)(ws + alloc((size_t)B_ * N_ * C2_ * 2));   // 64 MiB
  bf16_t* vsum = (bf16_t*)(ws + alloc((size_t)B_ * C_ * N_ * 2));    // 32 MiB
  bf16_t* abf  = (bf16_t*)(ws + alloc((size_t)B_ * N_ * N_ * 2));    // 64 MiB
  float*  bqk  = (float*)(ws + alloc((size_t)C2_ * 4));
  float*  bvs  = (float*)(ws + alloc((size_t)C_ * 4));
  (void)ws_size; (void)in_sizes; (void)n_in; (void)out_size;

  const dim3 blk(256);

  // 1) pack + passthrough
  pack_xt<<<dim3(N_ / 64, C_ / 64, B_ * 2), blk, 0, stream>>>(
      f_rgb, f_i, out_rgb, out_fi, xt);
  // 2) weights/biases -> bf16 / folded
  conv_wqk<<<dim3((C2_ * C2_) / (4 * 256)), blk, 0, stream>>>(
      wq, wk, (unsigned short*)wqk);
  conv_wvsum<<<dim3((C_ * C2_) / (4 * 256)), blk, 0, stream>>>(
      wv, (unsigned short*)wvs);
  conv_bias<<<dim3(C2_ / 256), blk, 0, stream>>>(bq, bk, bv, bqk, bvs);

  const long long sNN = (long long)N_ * C2_;      // 16777216
  const long long sCN = (long long)C_ * N_;       // 8388608

  // 3) G1: QKt[b][n][0:4096] = Xt . wqk^T + bqk   (bf16 out)
  gemm_bt<bf16_t><<<dim3(C2_ / 128, N_ / 128, B_), blk, 0, stream>>>(
      xt, wqk, qkt, C2_, C2_, C2_, C2_, sNN, 0, sNN, nullptr, bqk, 1.0f);

  // 4) GV: Vsum[b][c][m] = wvsum . Xt^T + bvsum   (bf16 out)
  gemm_bt<bf16_t><<<dim3(N_ / 128, C_ / 128, B_), blk, 0, stream>>>(
      wvs, xt, vsum, C2_, C2_, C2_, N_, 0, sNN, sCN, bvs, nullptr, 1.0f);

  // 5) G2: S[b][n][m] = Qt . Kt^T / 64 -> d_out attn region (fp32)
  gemm_bt<float><<<dim3(N_ / 128, N_ / 128, B_), blk, 0, stream>>>(
      qkt, qkt + C_, out_attn, C_, C2_, C2_, N_, sNN, sNN, sNN,
      nullptr, nullptr, 1.0f / 64.0f);

  // 6) softmax rows (in place) + bf16 copy
  softmax_rows<<<dim3(B_ * N_), blk, 0, stream>>>(out_attn, abf);

  // 7) G3: f_final[b][c][n] = Vsum . attn_bf^T (fp32)
  gemm_bt<float><<<dim3(N_ / 128, C_ / 128, B_), blk, 0, stream>>>(
      vsum, abf, out_ff, N_, N_, N_, N_, sCN, sNN, sCN,
      nullptr, nullptr, 1.0f);
}